// Round 8
// baseline (50.396 us; speedup 1.0000x reference)
//
#include <hip/hip_runtime.h>
#include <math.h>

#define B 8
#define H 384
#define W 384
#define HW (H*W)
#define NTOT (B*HW)
#define INF_I 10000
#define NWRK 256           // 8 images x 32 stripes of 12 rows
#define SROWS 12
#define RPAD 32            // bit-window rows above/below stripe kept in LDS
#define TOKEN_A 0x13572468u
#define TOKEN_B 0x2468ACEFu

// ws layout (bytes):
//   flag @ 0    : NWRK uint   (A/B handshake tokens)
//   part @ 4096 : NWRK*8 ull  (5 doubles per worker, 64B-padded)

__global__ __launch_bounds__(768) void k_all(const float* __restrict__ pred,
                                             const int* __restrict__ tgt,
                                             unsigned* __restrict__ flag,
                                             unsigned long long* __restrict__ part,
                                             float* __restrict__ out) {
    __shared__ unsigned long long bits[76 * 6];     // row-major 64-bit words
    __shared__ float lfp[12][412], lfn[12][412], lsA[12][412];
    __shared__ double wpart[12][5];
    __shared__ double cp[NWRK][5];
    __shared__ double cred[10];
    int tid = threadIdx.x;
    int bid = blockIdx.x;

    if (bid == NWRK) {
        // ================= combiner block =================
        if (tid < NWRK) {
            atomicExch(&flag[tid], TOKEN_A);
            while (atomicAdd(&flag[tid], 0u) != TOKEN_B) __builtin_amdgcn_s_sleep(4);
#pragma unroll
            for (int v = 0; v < 5; ++v)
                cp[tid][v] = __longlong_as_double(atomicAdd(&part[tid * 8 + v], 0ull));
        }
        __syncthreads();
        if (tid < 8) {                      // per-image dice term, fixed order
            double sp = 0, spt = 0, st = 0;
            for (int s = 0; s < 32; ++s) {
                int i = tid * 32 + s;
                sp += cp[i][1]; spt += cp[i][2]; st += cp[i][3];
            }
            cred[tid] = (2.0 * spt + 1e-5) / (sp + st + 1e-5);
        } else if (tid == 8) {
            double s = 0; for (int i = 0; i < NWRK; ++i) s += cp[i][0]; cred[8] = s;
        } else if (tid == 9) {
            double s = 0; for (int i = 0; i < NWRK; ++i) s += cp[i][4]; cred[9] = s;
        }
        __syncthreads();
        if (tid == 0) {
            double dice = 0.0;
            for (int bb = 0; bb < 8; ++bb) dice += cred[bb];
            dice /= 8.0;
            double bce = cred[8] / (double)NTOT;
            double loss1 = 0.5 * bce + (1.0 - dice);
            double loss2 = cred[9] / ((double)B * (double)B * (double)HW);
            out[0] = (float)(0.7 * loss1 + 0.03 * loss2);
        }
        return;
    }

    // ================= worker block: (image b, 12-row stripe) =================
    int b = bid >> 5, stripe = bid & 31;
    int row0 = stripe * SROWS;
    int pb = row0 - RPAD; if (pb < 0) pb = 0;
    int pe = row0 + SROWS + RPAD; if (pe > H) pe = H;
    int npix = (pe - pb) * W;
    const int* timg = tgt + b * HW;

    // ---- pack window bits (row-major u64 words), coalesced ballots ----
    for (int base = 0; base < npix; base += 768) {
        int lp = base + tid;
        int t = (lp < npix) ? (timg[pb * W + lp] != 0) : 0;
        unsigned long long m = __ballot(t);
        if (lp < npix && (lp & 63) == 0) bits[lp >> 6] = m;
    }
    __syncthreads();

    int wv = tid >> 6, lane = tid & 63;
    int h = row0 + wv;                      // one row per wave
    int hl = h - pb;
    int kup = hl, kdn = pe - 1 - h;
    float s_bce = 0.f, s_p = 0.f, s_pt = 0.f, s_t = 0.f;

    // ---- vertical EDT for this row via bit probes ----
    for (int g = 0; g < 6; ++g) {
        int w = g * 64 + lane;
        unsigned long long wc = bits[hl * 6 + g];
        int c = (int)((wc >> lane) & 1ull);
        int dP = c ? 0 : INF_I;
        int dN = c ? INF_I : 0;
        int kmax = kup > kdn ? kup : kdn;
        for (int k = 1; k <= kmax; ++k) {
            if (__all(dP < INF_I && dN < INF_I)) break;
            int vu = (k <= kup), vd = (k <= kdn);
            unsigned long long mu = vu ? bits[(hl - k) * 6 + g] : 0ull;
            unsigned long long md = vd ? bits[(hl + k) * 6 + g] : 0ull;
            int bu = (int)((mu >> lane) & 1ull);
            int bd = (int)((md >> lane) & 1ull);
            if (dP == INF_I && ((vu & bu) | (vd & bd))) dP = k;
            if (dN == INF_I && ((vu & (bu ^ 1)) | (vd & (bd ^ 1)))) dN = k;
        }
        // beyond-window fallback (exactness for any data; ~never on random data)
        bool needU = (pb > 0) && (dP > kup || dN > kup);
        bool needD = (pe < H) && (dP > kdn || dN > kdn);
        if (__any(needU || needD)) {
            if (needU)
                for (int r = pb - 1; r >= 0 && (dP > h - r || dN > h - r); --r) {
                    int tt = timg[r * W + w] != 0; int d = h - r;
                    if (tt) { if (d < dP) dP = d; } else { if (d < dN) dN = d; }
                }
            if (needD)
                for (int r = pe; r < H && (dP > r - h || dN > r - h); ++r) {
                    int tt = timg[r * W + w] != 0; int d = r - h;
                    if (tt) { if (d < dP) dP = d; } else { if (d < dN) dN = d; }
                }
        }
        int s = w + (w >> 4);
        lfp[wv][s] = (float)dP * (float)dP;   // exact: d<=1e4 -> d^2<=1e8 repr.
        lfn[wv][s] = (float)dN * (float)dN;
    }

    // ---- sumA for this row (all 8 images) + BCE/dice partials (own image) ----
    float sAcc[6];
#pragma unroll
    for (int g = 0; g < 6; ++g) sAcc[g] = 0.f;
    for (int bb = 0; bb < 8; ++bb) {
        const float* prow = pred + bb * HW + h * W;
        const int* trow = tgt + bb * HW + h * W;
#pragma unroll
        for (int g = 0; g < 6; ++g) {
            int w = g * 64 + lane;
            float x = prow[w];
            int t = trow[w];
            float e = expf(-fabsf(x));
            float r = 1.f / (1.f + e);
            float p = (x >= 0.f) ? r : 1.f - r;            // stable sigmoid
            sAcc[g] += t ? 1.f - p : p;
            if (bb == b) {
                s_bce += fmaxf(x, 0.f) + log1pf(e) - x * (float)t;
                s_p += p;
                if (t) { s_pt += p; s_t += 1.f; }
            }
        }
    }
#pragma unroll
    for (int g = 0; g < 6; ++g) {
        int w = g * 64 + lane;
        lsA[wv][w + (w >> 4)] = sAcc[g];
    }
    asm volatile("s_waitcnt lgkmcnt(0)" ::: "memory");  // wave-local LDS RAW

    // ---- row lower-envelope (17-tap window + provable full-row fallback) ----
    int base6 = 6 * lane - 8;
    float rp[22], rn[22];
#pragma unroll
    for (int r = 0; r < 22; ++r) {
        int j = base6 + r;
        j = j < 0 ? 0 : (j > W - 1 ? W - 1 : j);
        int s = j + (j >> 4);
        rp[r] = lfp[wv][s];
        rn[r] = lfn[wv][s];
    }
    const float DD[17] = {64.f,49.f,36.f,25.f,16.f,9.f,4.f,1.f,0.f,
                          1.f,4.f,9.f,16.f,25.f,36.f,49.f,64.f};
    float partial = 0.f;
#pragma unroll
    for (int q = 0; q < 6; ++q) {
        int i = 6 * lane + q;
        float Dp = 3.0e38f, Dn = 3.0e38f;
#pragma unroll
        for (int tt = 0; tt < 17; ++tt) {
            Dp = fminf(Dp, rp[q + tt] + DD[tt]);
            Dn = fminf(Dn, rn[q + tt] + DD[tt]);
        }
        if (Dp > 64.f || Dn > 64.f) {       // exactness not proven -> full row
            float fi = (float)i;
            for (int j = 0; j < W; ++j) {
                int s = j + (j >> 4);
                float d = fi - (float)j;
                Dp = fminf(Dp, fmaf(d, d, lfp[wv][s]));
                Dn = fminf(Dn, fmaf(d, d, lfn[wv][s]));
            }
        }
        float sdf = fabsf(sqrtf(Dp) - sqrtf(Dn));
        partial += sdf * lsA[wv][i + (i >> 4)];
    }

    // ---- block reduce (fixed order), publish, handshake ----
    double v0 = s_bce, v1 = s_p, v2 = s_pt, v3 = s_t, v4 = partial;
#pragma unroll
    for (int o = 32; o; o >>= 1) {
        v0 += __shfl_down(v0, o);
        v1 += __shfl_down(v1, o);
        v2 += __shfl_down(v2, o);
        v3 += __shfl_down(v3, o);
        v4 += __shfl_down(v4, o);
    }
    if (lane == 0) {
        wpart[wv][0] = v0; wpart[wv][1] = v1; wpart[wv][2] = v2;
        wpart[wv][3] = v3; wpart[wv][4] = v4;
    }
    __syncthreads();
    if (tid == 0) {
        double a0 = 0, a1 = 0, a2 = 0, a3 = 0, a4 = 0;
#pragma unroll
        for (int k = 0; k < 12; ++k) {
            a0 += wpart[k][0]; a1 += wpart[k][1]; a2 += wpart[k][2];
            a3 += wpart[k][3]; a4 += wpart[k][4];
        }
        atomicExch(&part[bid * 8 + 0], __double_as_longlong(a0));
        atomicExch(&part[bid * 8 + 1], __double_as_longlong(a1));
        atomicExch(&part[bid * 8 + 2], __double_as_longlong(a2));
        atomicExch(&part[bid * 8 + 3], __double_as_longlong(a3));
        atomicExch(&part[bid * 8 + 4], __double_as_longlong(a4));
        asm volatile("s_waitcnt vmcnt(0)" ::: "memory");
        while (atomicAdd(&flag[bid], 0u) != TOKEN_A) __builtin_amdgcn_s_sleep(2);
        atomicExch(&flag[bid], TOKEN_B);
    }
}

extern "C" void kernel_launch(void* const* d_in, const int* in_sizes, int n_in,
                              void* d_out, int out_size, void* d_ws, size_t ws_size,
                              hipStream_t stream) {
    const float* pred = (const float*)d_in[0];
    const int* tgt = (const int*)d_in[1];
    float* out = (float*)d_out;
    char* ws = (char*)d_ws;
    unsigned* flag = (unsigned*)ws;
    unsigned long long* part = (unsigned long long*)(ws + 4096);

    k_all<<<NWRK + 1, 768, 0, stream>>>(pred, tgt, flag, part, out);
}